// Round 5
// baseline (1924.450 us; speedup 1.0000x reference)
//
#include <hip/hip_runtime.h>
#include <hip/hip_bf16.h>

#define NN 100000     // nodes
#define NE 400000     // edges
#define DD 128        // feature dim
#define NG 4096       // graphs
#define NL 5          // layers
#define NF 11         // in features

// ---------------- preprocessing ----------------

__global__ void deg_kernel(const int* __restrict__ ei, int* __restrict__ deg) {
    int e = blockIdx.x * 256 + threadIdx.x;
    if (e < NE) atomicAdd(&deg[ei[NE + e]], 1);
}

// block scans 1024 elements (4 per thread), writes per-block total
__global__ void scan1_kernel(const int* __restrict__ deg, int* __restrict__ off,
                             int* __restrict__ bsums) {
    __shared__ int lds[256];
    int tid = threadIdx.x, b = blockIdx.x;
    int base = b * 1024 + tid * 4;
    int v[4];
#pragma unroll
    for (int q = 0; q < 4; ++q) {
        int i = base + q;
        v[q] = (i < NN) ? deg[i] : 0;
    }
    int s = v[0] + v[1] + v[2] + v[3];
    lds[tid] = s;
    __syncthreads();
    for (int o = 1; o < 256; o <<= 1) {
        int t2 = (tid >= o) ? lds[tid - o] : 0;
        __syncthreads();
        lds[tid] += t2;
        __syncthreads();
    }
    int p = lds[tid] - s;  // exclusive prefix for this thread
#pragma unroll
    for (int q = 0; q < 4; ++q) {
        int i = base + q;
        if (i < NN) off[i] = p;
        p += v[q];
    }
    if (tid == 255) bsums[b] = lds[255];
}

__global__ void scan2_kernel(int* __restrict__ bsums, int nb) {
    __shared__ int lds[128];
    int tid = threadIdx.x;
    int v = (tid < nb) ? bsums[tid] : 0;
    lds[tid] = v;
    __syncthreads();
    for (int o = 1; o < 128; o <<= 1) {
        int t2 = (tid >= o) ? lds[tid - o] : 0;
        __syncthreads();
        lds[tid] += t2;
        __syncthreads();
    }
    if (tid < nb) bsums[tid] = lds[tid] - v;  // exclusive
}

__global__ void finish_kernel(int* __restrict__ off, const int* __restrict__ bsums,
                              const int* __restrict__ deg, float* __restrict__ dinv) {
    int i = blockIdx.x * 256 + threadIdx.x;
    if (i == 0) off[NN] = NE;
    if (i < NN) {
        off[i] += bsums[i >> 10];
        dinv[i] = rsqrtf((float)deg[i] + 2.0f);
    }
}

// packed CSR record: .x = src | (dst&63)<<24, .y = bitcast(norm)
// (layer blocks are 64-aligned, so dst&63 is the block-local dst index)
__global__ void fill_kernel(const int* __restrict__ ei, const int* __restrict__ off,
                            int* __restrict__ cursor, int2* __restrict__ csr,
                            const float* __restrict__ dinv) {
    int e = blockIdx.x * 256 + threadIdx.x;
    if (e >= NE) return;
    int s = ei[e];
    int d = ei[NE + e];
    int pos = off[d] + atomicAdd(&cursor[d], 1);
    csr[pos] = make_int2(s | ((d & 63) << 24), __float_as_int(dinv[s] * dinv[d]));
}

// ---------------- expansion: h = log(x+1) @ We + be ----------------

__global__ void expand_kernel(const float* __restrict__ x, const float* __restrict__ We,
                              const float* __restrict__ be, float* __restrict__ h) {
    int t = blockIdx.x * 256 + threadIdx.x;  // t < NN*128
    int i = t >> 7, j = t & 127;
    float acc = be[j];
#pragma unroll
    for (int f = 0; f < NF; ++f) {
        acc += __logf(x[i * NF + f] + 1.0f) * We[f * DD + j];
    }
    h[t] = acc;
}

// ---------------- fused layer: hout = hin + relu((A_hat @ hin) @ W + b) ----------------
// Block = 64 nodes, 256 threads.
// Phase A0: gs[nl][j] = self_norm * hin  (scalar, coalesced, conflict-free)
// Phase A1: edge-parallel over (edge, col) tasks; ds_add_f32 atomics, bank = col%32
//           -> conflict-free; gathers coalesced (64 lanes = 64 consecutive cols).
// Phase B : register-tiled GEMM from gs (LD=129), W in 4-row double-buffered LDS.
// LDS = 64*129*4 + 2*4*128*4 = 37.1 KB -> 4 blocks/CU (16 waves, 50% occ).

__global__ __launch_bounds__(256) void layer_kernel(const float* __restrict__ hin,
                                                    float* __restrict__ hout,
                                                    const int* __restrict__ off,
                                                    const int2* __restrict__ csr,
                                                    const float* __restrict__ dinv,
                                                    const float* __restrict__ W,
                                                    const float* __restrict__ b) {
    __shared__ float gs[64 * 129];
    __shared__ float ws[2][4 * 128];
    const int tid = threadIdx.x;
    const int node0 = blockIdx.x * 64;

    // ---- Phase A0: self-term init ----
#pragma unroll
    for (int it = 0; it < 32; ++it) {
        int t = it * 256 + tid;
        int nl = t >> 7, j = t & 127;
        int node = node0 + nl;
        float v = 0.f;
        if (node < NN) {
            float di = dinv[node];
            v = 2.f * di * di * hin[(size_t)node * DD + j];
        }
        gs[nl * 129 + j] = v;
    }
    __syncthreads();

    // ---- Phase A1: edge-parallel scatter ----
    {
        const int eLo = off[node0];
        const int eHi = off[min(node0 + 64, NN)];
        const int lim = (eHi - eLo) * 128;
#pragma unroll 1
        for (int t0 = tid; t0 < lim; t0 += 1024) {
            int t1 = t0 + 256, t2 = t0 + 512, t3 = t0 + 768;
            // gather up to 4 independent (edge, col) tasks
            int2 r0, r1, r2, r3;
            float v0 = 0.f, v1 = 0.f, v2 = 0.f, v3 = 0.f;
            r0 = csr[eLo + (t0 >> 7)];
            v0 = hin[(size_t)(r0.x & 0xFFFFFF) * DD + (t0 & 127)];
            if (t1 < lim) { r1 = csr[eLo + (t1 >> 7)]; v1 = hin[(size_t)(r1.x & 0xFFFFFF) * DD + (t1 & 127)]; }
            if (t2 < lim) { r2 = csr[eLo + (t2 >> 7)]; v2 = hin[(size_t)(r2.x & 0xFFFFFF) * DD + (t2 & 127)]; }
            if (t3 < lim) { r3 = csr[eLo + (t3 >> 7)]; v3 = hin[(size_t)(r3.x & 0xFFFFFF) * DD + (t3 & 127)]; }
            atomicAdd(&gs[((r0.x >> 24) & 63) * 129 + (t0 & 127)], __int_as_float(r0.y) * v0);
            if (t1 < lim) atomicAdd(&gs[((r1.x >> 24) & 63) * 129 + (t1 & 127)], __int_as_float(r1.y) * v1);
            if (t2 < lim) atomicAdd(&gs[((r2.x >> 24) & 63) * 129 + (t2 & 127)], __int_as_float(r2.y) * v2);
            if (t3 < lim) atomicAdd(&gs[((r3.x >> 24) & 63) * 129 + (t3 & 127)], __int_as_float(r3.y) * v3);
        }
    }

    // preload W chunk 0 (rows 0..3) into ws[0]
    {
        float2 wv = *(const float2*)(W + tid * 2);
        *(float2*)&ws[0][tid * 2] = wv;
    }

    // ---- Phase B: gemm gs @ W, epilogue hout = hin + relu(. + b) ----
    const int cg = tid & 15;   // col group: cols cg*4+{0..3}, cg*4+64+{0..3}
    const int rg = tid >> 4;   // row group: rows rg + 16m, m=0..3
    float acc[4][8];
#pragma unroll
    for (int m = 0; m < 4; ++m)
#pragma unroll
        for (int q = 0; q < 8; ++q) acc[m][q] = 0.f;

#pragma unroll 1
    for (int kc = 0; kc < 32; ++kc) {
        const int cur = kc & 1;
        float2 wnext;
        const bool have = (kc + 1 < 32);
        if (have) wnext = *(const float2*)(W + (kc + 1) * 512 + tid * 2);
        __syncthreads();  // gs atomics (kc==0) + ws[cur] ready
#pragma unroll
        for (int kk = 0; kk < 4; ++kk) {
            const float* wrow = &ws[cur][kk * 128];
            float4 wlo = *(const float4*)(wrow + cg * 4);
            float4 whi = *(const float4*)(wrow + cg * 4 + 64);
            const int k = kc * 4 + kk;
#pragma unroll
            for (int m = 0; m < 4; ++m) {
                float gv = gs[(rg + (m << 4)) * 129 + k];
                acc[m][0] = fmaf(gv, wlo.x, acc[m][0]);
                acc[m][1] = fmaf(gv, wlo.y, acc[m][1]);
                acc[m][2] = fmaf(gv, wlo.z, acc[m][2]);
                acc[m][3] = fmaf(gv, wlo.w, acc[m][3]);
                acc[m][4] = fmaf(gv, whi.x, acc[m][4]);
                acc[m][5] = fmaf(gv, whi.y, acc[m][5]);
                acc[m][6] = fmaf(gv, whi.z, acc[m][6]);
                acc[m][7] = fmaf(gv, whi.w, acc[m][7]);
            }
        }
        if (have) *(float2*)&ws[cur ^ 1][tid * 2] = wnext;
    }

    float4 blo = *(const float4*)(b + cg * 4);
    float4 bhi = *(const float4*)(b + cg * 4 + 64);
#pragma unroll
    for (int m = 0; m < 4; ++m) {
        int r = rg + (m << 4);
        int row = node0 + r;
        if (row < NN) {
            size_t o = (size_t)row * DD + cg * 4;
            float4 hlo = *(const float4*)(hin + o);
            float4 hhi = *(const float4*)(hin + o + 64);
            hlo.x += fmaxf(acc[m][0] + blo.x, 0.f);
            hlo.y += fmaxf(acc[m][1] + blo.y, 0.f);
            hlo.z += fmaxf(acc[m][2] + blo.z, 0.f);
            hlo.w += fmaxf(acc[m][3] + blo.w, 0.f);
            hhi.x += fmaxf(acc[m][4] + bhi.x, 0.f);
            hhi.y += fmaxf(acc[m][5] + bhi.y, 0.f);
            hhi.z += fmaxf(acc[m][6] + bhi.z, 0.f);
            hhi.w += fmaxf(acc[m][7] + bhi.w, 0.f);
            *(float4*)(hout + o) = hlo;
            *(float4*)(hout + o + 64) = hhi;
        }
    }
}

// ---------------- pool: out[batch[i]] += h[i]  (batch sorted) ----------------

__global__ void pool_kernel(const float* __restrict__ h, const int* __restrict__ batch,
                            float* __restrict__ out) {
    int j = threadIdx.x;  // 128
    int n0 = blockIdx.x * 64;
    float acc = 0.f;
    int prev = -1;
    for (int n = 0; n < 64; ++n) {
        int i = n0 + n;
        if (i >= NN) break;
        int bi = batch[i];
        if (bi != prev) {
            if (prev >= 0) atomicAdd(&out[(size_t)prev * DD + j], acc);
            acc = 0.f;
            prev = bi;
        }
        acc += h[(size_t)i * DD + j];
    }
    if (prev >= 0) atomicAdd(&out[(size_t)prev * DD + j], acc);
}

// ---------------- launch ----------------

static inline size_t align_up(size_t x, size_t a) { return (x + a - 1) & ~(a - 1); }

extern "C" void kernel_launch(void* const* d_in, const int* in_sizes, int n_in,
                              void* d_out, int out_size, void* d_ws, size_t ws_size,
                              hipStream_t stream) {
    const float* x   = (const float*)d_in[0];
    const int*   ei  = (const int*)d_in[1];
    const int*   bat = (const int*)d_in[2];
    const float* We  = (const float*)d_in[4];
    const float* be  = (const float*)d_in[5];
    const float* Wg  = (const float*)d_in[6];
    const float* bg  = (const float*)d_in[7];
    float* out = (float*)d_out;

    // workspace carve-up
    char* p = (char*)d_ws;
    size_t o = 0;
    float* h0 = (float*)(p + o);      o = align_up(o + (size_t)NN * DD * 4, 512);
    float* h1 = (float*)(p + o);      o = align_up(o + (size_t)NN * DD * 4, 512);
    float* dinv = (float*)(p + o);    o = align_up(o + (size_t)NN * 4, 512);
    int* deg = (int*)(p + o);         o = align_up(o + (size_t)NN * 4, 512);
    int* cursor = (int*)(p + o);      o = align_up(o + (size_t)NN * 4, 512);
    int* off = (int*)(p + o);         o = align_up(o + (size_t)(NN + 1) * 4, 512);
    int* bsums = (int*)(p + o);       o = align_up(o + 512, 512);
    int2* csr = (int2*)(p + o);       o = align_up(o + (size_t)NE * 8, 512);
    (void)ws_size; (void)in_sizes; (void)n_in; (void)out_size;

    float* hbuf[2] = {h0, h1};

    const int GRID_E = (NE + 255) / 256;          // 1563
    const int GRID_SCAN1 = (NN + 1023) / 1024;    // 98
    const int GRID_N256 = (NN + 255) / 256;       // 391
    const int GRID_ND = (size_t)NN * DD / 256;    // 50000
    const int GRID_LAYER = (NN + 63) / 64;        // 1563
    const int GRID_POOL = (NN + 63) / 64;         // 1563

    // zero deg + cursor (ws is poisoned 0xAA each call)
    hipMemsetAsync(deg, 0, (size_t)NN * 4, stream);
    hipMemsetAsync(cursor, 0, (size_t)NN * 4, stream);
    hipMemsetAsync(out, 0, (size_t)NG * DD * 4, stream);

    deg_kernel<<<GRID_E, 256, 0, stream>>>(ei, deg);
    scan1_kernel<<<GRID_SCAN1, 256, 0, stream>>>(deg, off, bsums);
    scan2_kernel<<<1, 128, 0, stream>>>(bsums, GRID_SCAN1);
    finish_kernel<<<GRID_N256, 256, 0, stream>>>(off, bsums, deg, dinv);
    fill_kernel<<<GRID_E, 256, 0, stream>>>(ei, off, cursor, csr, dinv);

    expand_kernel<<<GRID_ND, 256, 0, stream>>>(x, We, be, h0);

    for (int l = 0; l < NL; ++l) {
        const float* hin = hbuf[l & 1];
        float* hout = hbuf[(l & 1) ^ 1];
        layer_kernel<<<GRID_LAYER, 256, 0, stream>>>(hin, hout, off, csr, dinv,
                                                     Wg + (size_t)l * DD * DD,
                                                     bg + (size_t)l * DD);
    }

    pool_kernel<<<GRID_POOL, 128, 0, stream>>>(hbuf[NL & 1], bat, out);
}

// Round 6
// 655.397 us; speedup vs baseline: 2.9363x; 2.9363x over previous
//
#include <hip/hip_runtime.h>
#include <hip/hip_bf16.h>

#define NN 100000     // nodes
#define NE 400000     // edges
#define DD 128        // feature dim
#define NG 4096       // graphs
#define NL 5          // layers
#define NF 11         // in features

// ---------------- preprocessing ----------------

__global__ void deg_kernel(const int* __restrict__ ei, int* __restrict__ deg) {
    int e = blockIdx.x * 256 + threadIdx.x;
    if (e < NE) atomicAdd(&deg[ei[NE + e]], 1);
}

// block scans 1024 elements (4 per thread), writes per-block total
__global__ void scan1_kernel(const int* __restrict__ deg, int* __restrict__ off,
                             int* __restrict__ bsums) {
    __shared__ int lds[256];
    int tid = threadIdx.x, b = blockIdx.x;
    int base = b * 1024 + tid * 4;
    int v[4];
#pragma unroll
    for (int q = 0; q < 4; ++q) {
        int i = base + q;
        v[q] = (i < NN) ? deg[i] : 0;
    }
    int s = v[0] + v[1] + v[2] + v[3];
    lds[tid] = s;
    __syncthreads();
    for (int o = 1; o < 256; o <<= 1) {
        int t2 = (tid >= o) ? lds[tid - o] : 0;
        __syncthreads();
        lds[tid] += t2;
        __syncthreads();
    }
    int p = lds[tid] - s;  // exclusive prefix for this thread
#pragma unroll
    for (int q = 0; q < 4; ++q) {
        int i = base + q;
        if (i < NN) off[i] = p;
        p += v[q];
    }
    if (tid == 255) bsums[b] = lds[255];
}

__global__ void scan2_kernel(int* __restrict__ bsums, int nb) {
    __shared__ int lds[128];
    int tid = threadIdx.x;
    int v = (tid < nb) ? bsums[tid] : 0;
    lds[tid] = v;
    __syncthreads();
    for (int o = 1; o < 128; o <<= 1) {
        int t2 = (tid >= o) ? lds[tid - o] : 0;
        __syncthreads();
        lds[tid] += t2;
        __syncthreads();
    }
    if (tid < nb) bsums[tid] = lds[tid] - v;  // exclusive
}

__global__ void finish_kernel(int* __restrict__ off, const int* __restrict__ bsums,
                              const int* __restrict__ deg, float* __restrict__ dinv) {
    int i = blockIdx.x * 256 + threadIdx.x;
    if (i == 0) off[NN] = NE;
    if (i < NN) {
        off[i] += bsums[i >> 10];
        dinv[i] = rsqrtf((float)deg[i] + 2.0f);
    }
}

// packed CSR record: .x = src index, .y = bitcast(norm)
__global__ void fill_kernel(const int* __restrict__ ei, const int* __restrict__ off,
                            int* __restrict__ cursor, int2* __restrict__ csr,
                            const float* __restrict__ dinv) {
    int e = blockIdx.x * 256 + threadIdx.x;
    if (e >= NE) return;
    int s = ei[e];
    int d = ei[NE + e];
    int pos = off[d] + atomicAdd(&cursor[d], 1);
    csr[pos] = make_int2(s, __float_as_int(dinv[s] * dinv[d]));
}

// ---------------- expansion: h = log(x+1) @ We + be ----------------

__global__ void expand_kernel(const float* __restrict__ x, const float* __restrict__ We,
                              const float* __restrict__ be, float* __restrict__ h) {
    int t = blockIdx.x * 256 + threadIdx.x;  // t < NN*128
    int i = t >> 7, j = t & 127;
    float acc = be[j];
#pragma unroll
    for (int f = 0; f < NF; ++f) {
        acc += __logf(x[i * NF + f] + 1.0f) * We[f * DD + j];
    }
    h[t] = acc;
}

// ---------------- fused layer: hout = hin + relu((A_hat @ hin) @ W + b) ----------------
// Block = 64 nodes, 256 threads.
// Phase A: aggregate into LDS gs (32 lanes/node, float4/lane); PREDICATED 4-unroll:
//          always 4 independent gathers in flight (clamped idx + zeroed tail weight).
// Phase B: register-tiled GEMM; W read directly from global (L1/L2-resident, 4-lane
//          broadcast per float4) -> NO ws staging, NO barriers after the single sync.
// LDS = 64*129*4 = 33 KB -> 4 blocks/CU (16 waves, 50% occupancy).

__global__ __launch_bounds__(256) void layer_kernel(const float* __restrict__ hin,
                                                    float* __restrict__ hout,
                                                    const int* __restrict__ off,
                                                    const int2* __restrict__ csr,
                                                    const float* __restrict__ dinv,
                                                    const float* __restrict__ W,
                                                    const float* __restrict__ b) {
    __shared__ float gs[64 * 129];
    const int tid = threadIdx.x;
    const int node0 = blockIdx.x * 64;
    const float4* __restrict__ h4 = (const float4*)hin;

    // ---- Phase A: aggregate 64 nodes into gs ----
    const int jj = tid & 31;
    const int sub = tid >> 5;  // 0..7
#pragma unroll 1
    for (int p = 0; p < 8; ++p) {
        const int nl = p * 8 + sub;        // local node 0..63
        const int node = node0 + nl;
        float4 acc = make_float4(0.f, 0.f, 0.f, 0.f);
        if (node < NN) {
            float di = dinv[node];
            float sn = 2.0f * di * di;
            float4 hv = h4[(size_t)node * 32 + jj];
            acc = make_float4(sn * hv.x, sn * hv.y, sn * hv.z, sn * hv.w);
            const int e0 = off[node];
            const int e1 = off[node + 1];
#pragma unroll 1
            for (int e = e0; e < e1; e += 4) {
                const int eL = e1 - 1;
                int i1 = min(e + 1, eL), i2 = min(e + 2, eL), i3 = min(e + 3, eL);
                int2 p0 = csr[e], p1 = csr[i1], p2 = csr[i2], p3 = csr[i3];
                float4 v0 = h4[(size_t)p0.x * 32 + jj];
                float4 v1 = h4[(size_t)p1.x * 32 + jj];
                float4 v2 = h4[(size_t)p2.x * 32 + jj];
                float4 v3 = h4[(size_t)p3.x * 32 + jj];
                float w0 = __int_as_float(p0.y);
                float w1 = (e + 1 < e1) ? __int_as_float(p1.y) : 0.f;
                float w2 = (e + 2 < e1) ? __int_as_float(p2.y) : 0.f;
                float w3 = (e + 3 < e1) ? __int_as_float(p3.y) : 0.f;
                acc.x = fmaf(w0, v0.x, acc.x); acc.y = fmaf(w0, v0.y, acc.y);
                acc.z = fmaf(w0, v0.z, acc.z); acc.w = fmaf(w0, v0.w, acc.w);
                acc.x = fmaf(w1, v1.x, acc.x); acc.y = fmaf(w1, v1.y, acc.y);
                acc.z = fmaf(w1, v1.z, acc.z); acc.w = fmaf(w1, v1.w, acc.w);
                acc.x = fmaf(w2, v2.x, acc.x); acc.y = fmaf(w2, v2.y, acc.y);
                acc.z = fmaf(w2, v2.z, acc.z); acc.w = fmaf(w2, v2.w, acc.w);
                acc.x = fmaf(w3, v3.x, acc.x); acc.y = fmaf(w3, v3.y, acc.y);
                acc.z = fmaf(w3, v3.z, acc.z); acc.w = fmaf(w3, v3.w, acc.w);
            }
        }
        *(float4*)&gs[nl * 129 + jj * 4] = acc;
    }
    __syncthreads();  // gs ready; no further barriers needed

    // ---- Phase B: gemm gs @ W (W from global), epilogue hout = hin + relu(. + b) ----
    const int cg = tid & 15;   // col group: cols cg*4+{0..3}, cg*4+64+{0..3}
    const int rg = tid >> 4;   // row group: rows rg + 16m, m=0..3
    float acc[4][8];
#pragma unroll
    for (int m = 0; m < 4; ++m)
#pragma unroll
        for (int q = 0; q < 8; ++q) acc[m][q] = 0.f;

#pragma unroll 8
    for (int k = 0; k < 128; ++k) {
        float4 wlo = *(const float4*)(W + k * 128 + cg * 4);
        float4 whi = *(const float4*)(W + k * 128 + cg * 4 + 64);
#pragma unroll
        for (int m = 0; m < 4; ++m) {
            float gv = gs[(rg + (m << 4)) * 129 + k];
            acc[m][0] = fmaf(gv, wlo.x, acc[m][0]);
            acc[m][1] = fmaf(gv, wlo.y, acc[m][1]);
            acc[m][2] = fmaf(gv, wlo.z, acc[m][2]);
            acc[m][3] = fmaf(gv, wlo.w, acc[m][3]);
            acc[m][4] = fmaf(gv, whi.x, acc[m][4]);
            acc[m][5] = fmaf(gv, whi.y, acc[m][5]);
            acc[m][6] = fmaf(gv, whi.z, acc[m][6]);
            acc[m][7] = fmaf(gv, whi.w, acc[m][7]);
        }
    }

    float4 blo = *(const float4*)(b + cg * 4);
    float4 bhi = *(const float4*)(b + cg * 4 + 64);
#pragma unroll
    for (int m = 0; m < 4; ++m) {
        int r = rg + (m << 4);
        int row = node0 + r;
        if (row < NN) {
            size_t o = (size_t)row * DD + cg * 4;
            float4 hlo = *(const float4*)(hin + o);
            float4 hhi = *(const float4*)(hin + o + 64);
            hlo.x += fmaxf(acc[m][0] + blo.x, 0.f);
            hlo.y += fmaxf(acc[m][1] + blo.y, 0.f);
            hlo.z += fmaxf(acc[m][2] + blo.z, 0.f);
            hlo.w += fmaxf(acc[m][3] + blo.w, 0.f);
            hhi.x += fmaxf(acc[m][4] + bhi.x, 0.f);
            hhi.y += fmaxf(acc[m][5] + bhi.y, 0.f);
            hhi.z += fmaxf(acc[m][6] + bhi.z, 0.f);
            hhi.w += fmaxf(acc[m][7] + bhi.w, 0.f);
            *(float4*)(hout + o) = hlo;
            *(float4*)(hout + o + 64) = hhi;
        }
    }
}

// ---------------- pool: out[batch[i]] += h[i]  (batch sorted) ----------------

__global__ void pool_kernel(const float* __restrict__ h, const int* __restrict__ batch,
                            float* __restrict__ out) {
    int j = threadIdx.x;  // 128
    int n0 = blockIdx.x * 64;
    float acc = 0.f;
    int prev = -1;
    for (int n = 0; n < 64; ++n) {
        int i = n0 + n;
        if (i >= NN) break;
        int bi = batch[i];
        if (bi != prev) {
            if (prev >= 0) atomicAdd(&out[(size_t)prev * DD + j], acc);
            acc = 0.f;
            prev = bi;
        }
        acc += h[(size_t)i * DD + j];
    }
    if (prev >= 0) atomicAdd(&out[(size_t)prev * DD + j], acc);
}

// ---------------- launch ----------------

static inline size_t align_up(size_t x, size_t a) { return (x + a - 1) & ~(a - 1); }

extern "C" void kernel_launch(void* const* d_in, const int* in_sizes, int n_in,
                              void* d_out, int out_size, void* d_ws, size_t ws_size,
                              hipStream_t stream) {
    const float* x   = (const float*)d_in[0];
    const int*   ei  = (const int*)d_in[1];
    const int*   bat = (const int*)d_in[2];
    const float* We  = (const float*)d_in[4];
    const float* be  = (const float*)d_in[5];
    const float* Wg  = (const float*)d_in[6];
    const float* bg  = (const float*)d_in[7];
    float* out = (float*)d_out;

    // workspace carve-up
    char* p = (char*)d_ws;
    size_t o = 0;
    float* h0 = (float*)(p + o);      o = align_up(o + (size_t)NN * DD * 4, 512);
    float* h1 = (float*)(p + o);      o = align_up(o + (size_t)NN * DD * 4, 512);
    float* dinv = (float*)(p + o);    o = align_up(o + (size_t)NN * 4, 512);
    int* deg = (int*)(p + o);         o = align_up(o + (size_t)NN * 4, 512);
    int* cursor = (int*)(p + o);      o = align_up(o + (size_t)NN * 4, 512);
    int* off = (int*)(p + o);         o = align_up(o + (size_t)(NN + 1) * 4, 512);
    int* bsums = (int*)(p + o);       o = align_up(o + 512, 512);
    int2* csr = (int2*)(p + o);       o = align_up(o + (size_t)NE * 8, 512);
    (void)ws_size; (void)in_sizes; (void)n_in; (void)out_size;

    float* hbuf[2] = {h0, h1};

    const int GRID_E = (NE + 255) / 256;          // 1563
    const int GRID_SCAN1 = (NN + 1023) / 1024;    // 98
    const int GRID_N256 = (NN + 255) / 256;       // 391
    const int GRID_ND = (size_t)NN * DD / 256;    // 50000
    const int GRID_LAYER = (NN + 63) / 64;        // 1563
    const int GRID_POOL = (NN + 63) / 64;         // 1563

    // zero deg + cursor (ws is poisoned 0xAA each call)
    hipMemsetAsync(deg, 0, (size_t)NN * 4, stream);
    hipMemsetAsync(cursor, 0, (size_t)NN * 4, stream);
    hipMemsetAsync(out, 0, (size_t)NG * DD * 4, stream);

    deg_kernel<<<GRID_E, 256, 0, stream>>>(ei, deg);
    scan1_kernel<<<GRID_SCAN1, 256, 0, stream>>>(deg, off, bsums);
    scan2_kernel<<<1, 128, 0, stream>>>(bsums, GRID_SCAN1);
    finish_kernel<<<GRID_N256, 256, 0, stream>>>(off, bsums, deg, dinv);
    fill_kernel<<<GRID_E, 256, 0, stream>>>(ei, off, cursor, csr, dinv);

    expand_kernel<<<GRID_ND, 256, 0, stream>>>(x, We, be, h0);

    for (int l = 0; l < NL; ++l) {
        const float* hin = hbuf[l & 1];
        float* hout = hbuf[(l & 1) ^ 1];
        layer_kernel<<<GRID_LAYER, 256, 0, stream>>>(hin, hout, off, csr, dinv,
                                                     Wg + (size_t)l * DD * DD,
                                                     bg + (size_t)l * DD);
    }

    pool_kernel<<<GRID_POOL, 128, 0, stream>>>(hbuf[NL & 1], bat, out);
}